// Round 9
// baseline (324.750 us; speedup 1.0000x reference)
//
#include <hip/hip_runtime.h>
#include <hip/hip_bf16.h>

#define NN 10000
#define EE 640000
#define CIN 128
#define COUT 128
#define HH 256
#define SLOT 160
#define BN_EPS 1e-5f
#define XPITCH 136   // shorts per staged x row (+8 pad)
#define HPITCH 260   // shorts per hbuf row: 130 dwords, stride 2 banks mod 32

typedef __attribute__((ext_vector_type(8))) short short8x;
typedef __attribute__((ext_vector_type(4))) float floatx4;

// Static device scratch. g_cnt is self-restoring: zeroed by edge_kernel after
// use each call (first call sees .bss zeros), so scatter never needs a zeroed
// pass and prep work merges with scatter (independent).
__device__ float          g_A[NN * HH];            // fp32 node term A = xn@(W1t-W1b)+b1
__device__ unsigned short g_Bb[NN * HH];           // bf16 node term B = xn@W1b
__device__ int            g_cnt[NN];               // per-node edge count
__device__ int            g_slots[NN * SLOT + 64]; // src ids, slotted by dst
__device__ unsigned short g_W2f[8 * 8 * 64 * 8];   // W2 bf16, MFMA B-frag order
__device__ unsigned short g_W1f[32 * 4 * 64 * 8];  // [W1t-W1b | W1b] bf16, B-frag order

__device__ __forceinline__ unsigned short f2bf(float f) {
    unsigned u = __float_as_uint(f);
    u += 0x7fffu + ((u >> 16) & 1u);   // RNE
    return (unsigned short)(u >> 16);
}
__device__ __forceinline__ float bf2f(unsigned short h) {
    return __uint_as_float(((unsigned)h) << 16);
}
// Packed f32x2 -> bf16x2 (v_cvt_pk_bf16_f32 on gfx950).
__device__ __forceinline__ unsigned pkbf(float a, float b) {
    __hip_bfloat162 t = __float22bfloat162_rn(make_float2(a, b));
    union { __hip_bfloat162 h; unsigned u; } cv; cv.h = t;
    return cv.u;
}

// Merged prep + scatter (independent work, no intra-kernel ordering needed).
// blocks 0..15: W2f swizzle; 16..47: W1 fold+swizzle; 48..672: edge scatter.
__global__ void prepscatter_kernel(const float* __restrict__ W1,
                                   const float* __restrict__ W2,
                                   const int* __restrict__ ei) {
    const int b = blockIdx.x, tid = threadIdx.x;
    if (b < 16) {
        int idx = b * 256 + tid;               // 0..4095
        int lane = idx & 63;
        int quad = lane >> 4, m = lane & 15;
        int t = idx >> 9, k0 = (idx >> 6) & 7;
        unsigned short frag[8];
        #pragma unroll
        for (int j = 0; j < 8; j++)
            frag[j] = f2bf(W2[(k0 * 32 + quad * 8 + j) * COUT + t * 16 + m]);
        *(short8x*)(g_W2f + (size_t)idx * 8) = *(short8x*)frag;
        return;
    }
    if (b < 48) {
        int idx = (b - 16) * 256 + tid;        // 0..8191
        int lane = idx & 63;
        int quad = lane >> 4, m = lane & 15;
        int t = idx >> 8, k0 = (idx >> 6) & 3;
        int c = t * 16 + m;                    // global col 0..511
        unsigned short frag[8];
        #pragma unroll
        for (int j = 0; j < 8; j++) {
            int k = k0 * 32 + quad * 8 + j;
            float v = (c < 256) ? (W1[k * HH + c] - W1[(k + CIN) * HH + c])
                                : W1[(k + CIN) * HH + (c - 256)];
            frag[j] = f2bf(v);
        }
        *(short8x*)(g_W1f + (size_t)idx * 8) = *(short8x*)frag;
        return;
    }
    // Scatter: 625 blocks x 256 threads x 4 edges = 640000 exactly.
    int e = ((b - 48) * 256 + tid) * 4;
    int4 s4 = *(const int4*)(ei + e);
    int4 d4 = *(const int4*)(ei + EE + e);
    int p;
    p = atomicAdd(&g_cnt[d4.x], 1); if (p < SLOT) g_slots[d4.x * SLOT + p] = s4.x;
    p = atomicAdd(&g_cnt[d4.y], 1); if (p < SLOT) g_slots[d4.y * SLOT + p] = s4.y;
    p = atomicAdd(&g_cnt[d4.z], 1); if (p < SLOT) g_slots[d4.z * SLOT + p] = s4.z;
    p = atomicAdd(&g_cnt[d4.w], 1); if (p < SLOT) g_slots[d4.w * SLOT + p] = s4.w;
}

// Stage 1 via MFMA: [A|B] = (xh+xl) @ W1f, 32 nodes/block (r7-proven).
__global__ __launch_bounds__(256) void stage1_kernel(
    const float* __restrict__ x, const float* __restrict__ gamma,
    const float* __restrict__ beta, const float* __restrict__ mean,
    const float* __restrict__ var, const float* __restrict__ b1)
{
    __shared__ unsigned short xh[32 * XPITCH];
    __shared__ unsigned short xl[32 * XPITCH];
    __shared__ float s_lds[CIN], t_lds[CIN];
    const int tid = threadIdx.x;
    const int w = tid >> 6, lane = tid & 63;
    const int m = lane & 15, quad = lane >> 4;
    if (tid < CIN) {
        float s = gamma[tid] * rsqrtf(var[tid] + BN_EPS);
        s_lds[tid] = s;
        t_lds[tid] = beta[tid] - mean[tid] * s;
    }
    __syncthreads();
    const int mbase = blockIdx.x * 32;
    #pragma unroll
    for (int it = 0; it < 4; it++) {
        int slot = it * 256 + tid;
        int n = slot >> 5;
        int k = (slot & 31) * 4;
        int node = mbase + n;
        float4 v = make_float4(0.f, 0.f, 0.f, 0.f);
        if (node < NN) v = *(const float4*)(x + (size_t)node * CIN + k);
        float f[4] = {v.x, v.y, v.z, v.w};
        ushort4 uh, ul;
        unsigned short hb;
        float fn;
        fn = f[0] * s_lds[k + 0] + t_lds[k + 0]; hb = f2bf(fn); uh.x = hb; ul.x = f2bf(fn - bf2f(hb));
        fn = f[1] * s_lds[k + 1] + t_lds[k + 1]; hb = f2bf(fn); uh.y = hb; ul.y = f2bf(fn - bf2f(hb));
        fn = f[2] * s_lds[k + 2] + t_lds[k + 2]; hb = f2bf(fn); uh.z = hb; ul.z = f2bf(fn - bf2f(hb));
        fn = f[3] * s_lds[k + 3] + t_lds[k + 3]; hb = f2bf(fn); uh.w = hb; ul.w = f2bf(fn - bf2f(hb));
        *(ushort4*)(xh + n * XPITCH + k) = uh;
        *(ushort4*)(xl + n * XPITCH + k) = ul;
    }
    __syncthreads();

    floatx4 acc[2][8];
    #pragma unroll
    for (int mt = 0; mt < 2; mt++)
        #pragma unroll
        for (int nt = 0; nt < 8; nt++)
            acc[mt][nt] = (floatx4){0.f, 0.f, 0.f, 0.f};

    #pragma unroll
    for (int k0 = 0; k0 < 4; k0++) {
        short8x wf[8];
        #pragma unroll
        for (int nt = 0; nt < 8; nt++) {
            int t = w * 8 + nt;
            wf[nt] = *(const short8x*)(g_W1f + (size_t)((t * 4 + k0) * 64 + lane) * 8);
        }
        #pragma unroll
        for (int mt = 0; mt < 2; mt++) {
            const unsigned short* rp = xh + (mt * 16 + m) * XPITCH + k0 * 32 + quad * 8;
            const unsigned short* lp = xl + (mt * 16 + m) * XPITCH + k0 * 32 + quad * 8;
            short8x ah = *(const short8x*)rp;
            short8x al = *(const short8x*)lp;
            #pragma unroll
            for (int nt = 0; nt < 8; nt++) {
                acc[mt][nt] = __builtin_amdgcn_mfma_f32_16x16x32_bf16(al, wf[nt], acc[mt][nt], 0, 0, 0);
                acc[mt][nt] = __builtin_amdgcn_mfma_f32_16x16x32_bf16(ah, wf[nt], acc[mt][nt], 0, 0, 0);
            }
        }
    }
    const int colbase = w * 128;
    #pragma unroll
    for (int mt = 0; mt < 2; mt++) {
        #pragma unroll
        for (int nt = 0; nt < 8; nt++) {
            int col = colbase + nt * 16 + m;
            #pragma unroll
            for (int j = 0; j < 4; j++) {
                int node = mbase + mt * 16 + quad * 4 + j;
                if (node < NN) {
                    float v = acc[mt][nt][j];
                    if (col < 256) g_A[(size_t)node * HH + col] = v + b1[col];
                    else           g_Bb[(size_t)node * HH + (col - 256)] = f2bf(v);
                }
            }
        }
    }
}

// Main kernel: 256 threads = 4 waves x 32 channels; 64-edge periods.
// Wave w converts rows w*16..w*16+15 (guard tb+w*16<deg matches the MFMA
// tile-skip) and runs mt=0..3 tiles x nt=0..1 vs register B-frags.
// LDS traffic per edge halved vs 16-ch waves. g_cnt self-restored to 0.
__global__ __launch_bounds__(256, 4) void edge_kernel(const float* __restrict__ b2,
                                                      float* __restrict__ out)
{
    __shared__ unsigned short hbuf[64 * HPITCH];   // 33.3 KB
    __shared__ int sbuf[192];                      // zero-padded past deg
    const int tid = threadIdx.x;
    const int w = tid >> 6, lane = tid & 63;
    const int m = lane & 15, quad = lane >> 4;
    const unsigned laneoff = (unsigned)lane << 3;  // lane*8 bytes

    short8x bfrag[2][8];
    #pragma unroll
    for (int nt = 0; nt < 2; nt++)
        #pragma unroll
        for (int k0 = 0; k0 < 8; k0++)
            bfrag[nt][k0] = *(const short8x*)(g_W2f +
                (size_t)(((w * 2 + nt) * 8 + k0) * 64 + lane) * 8);
    const float b2v0 = b2[w * 32 + m];
    const float b2v1 = b2[w * 32 + 16 + m];

    for (int g = 0; g < 4; g++) {
        const int node = blockIdx.x * 4 + g;
        int deg = g_cnt[node]; if (deg > SLOT) deg = SLOT;
        const float4 av = *(const float4*)(g_A + (size_t)node * HH + lane * 4);
        __syncthreads();                  // prev node done; all waves read deg
        if (tid == 0) g_cnt[node] = 0;    // self-restore for next call's scatter
        if (tid < 192) sbuf[tid] = (tid < deg) ? g_slots[node * SLOT + tid] : 0;
        __syncthreads();                  // sbuf ready
        float rm0 = -INFINITY, rm1 = -INFINITY;
        const int ntp = (deg + 63) >> 6;
        for (int p = 0; p < ntp; p++) {
            const int tb = p << 6;
            if (tb + w * 16 < deg) {      // wave-uniform: skip all-pad row groups
                #pragma unroll
                for (int h = 0; h < 2; h++) {
                    uint2 bv[8];
                    #pragma unroll
                    for (int q = 0; q < 8; q++) {
                        int sv = sbuf[tb + w * 16 + h * 8 + q];
                        bv[q] = *(const uint2*)((const char*)g_Bb +
                                                (((unsigned)sv << 9) | laneoff));
                    }
                    #pragma unroll
                    for (int q = 0; q < 8; q++) {
                        int r = w * 16 + h * 8 + q;
                        uint2 b = bv[q];
                        float f0 = __uint_as_float(b.x << 16);
                        float f1 = __uint_as_float(b.x & 0xffff0000u);
                        float f2 = __uint_as_float(b.y << 16);
                        float f3 = __uint_as_float(b.y & 0xffff0000u);
                        float h0 = fmaxf(av.x + f0, 0.f);
                        float h1 = fmaxf(av.y + f1, 0.f);
                        float h2 = fmaxf(av.z + f2, 0.f);
                        float h3 = fmaxf(av.w + f3, 0.f);
                        uint2 hv;
                        hv.x = pkbf(h0, h1);
                        hv.y = pkbf(h2, h3);
                        *(uint2*)(hbuf + r * HPITCH + lane * 4) = hv;
                    }
                }
            }
            __syncthreads();              // hbuf(p) ready
            #pragma unroll
            for (int mt = 0; mt < 4; mt++) {
                if (tb + mt * 16 < deg) { // block-uniform tile-valid check
                    const unsigned short* ha = hbuf + (mt * 16 + m) * HPITCH + quad * 8;
                    floatx4 acc0 = {0.f, 0.f, 0.f, 0.f};
                    floatx4 acc1 = {0.f, 0.f, 0.f, 0.f};
                    #pragma unroll
                    for (int k0 = 0; k0 < 8; k0++) {
                        short8x af = *(const short8x*)(ha + k0 * 32);
                        acc0 = __builtin_amdgcn_mfma_f32_16x16x32_bf16(af, bfrag[0][k0], acc0, 0, 0, 0);
                        acc1 = __builtin_amdgcn_mfma_f32_16x16x32_bf16(af, bfrag[1][k0], acc1, 0, 0, 0);
                    }
                    const int rowbase = tb + mt * 16 + quad * 4;
                    if (rowbase + 4 <= deg) {
                        rm0 = fmaxf(rm0, fmaxf(fmaxf(acc0[0], acc0[1]), fmaxf(acc0[2], acc0[3])));
                        rm1 = fmaxf(rm1, fmaxf(fmaxf(acc1[0], acc1[1]), fmaxf(acc1[2], acc1[3])));
                    } else {
                        #pragma unroll
                        for (int j = 0; j < 4; j++) {
                            if (rowbase + j < deg) {
                                rm0 = fmaxf(rm0, acc0[j]);
                                rm1 = fmaxf(rm1, acc1[j]);
                            }
                        }
                    }
                }
            }
            __syncthreads();              // all waves done reading hbuf(p)
        }
        rm0 = fmaxf(rm0, __shfl_xor(rm0, 16));
        rm0 = fmaxf(rm0, __shfl_xor(rm0, 32));
        rm1 = fmaxf(rm1, __shfl_xor(rm1, 16));
        rm1 = fmaxf(rm1, __shfl_xor(rm1, 32));
        if (quad == 0) {
            float v0 = (deg > 0) ? fmaxf(rm0 + b2v0, 0.f) : 0.f;
            float v1 = (deg > 0) ? fmaxf(rm1 + b2v1, 0.f) : 0.f;
            out[(size_t)node * COUT + w * 32 + m] = v0;
            out[(size_t)node * COUT + w * 32 + 16 + m] = v1;
        }
    }
}

extern "C" void kernel_launch(void* const* d_in, const int* in_sizes, int n_in,
                              void* d_out, int out_size, void* d_ws, size_t ws_size,
                              hipStream_t stream) {
    const float* x      = (const float*)d_in[0];
    const int*   ei     = (const int*)d_in[1];
    const float* gamma  = (const float*)d_in[2];
    const float* beta   = (const float*)d_in[3];
    const float* mean   = (const float*)d_in[4];
    const float* var    = (const float*)d_in[5];
    const float* W1     = (const float*)d_in[6];
    const float* b1     = (const float*)d_in[7];
    const float* W2     = (const float*)d_in[8];
    const float* b2     = (const float*)d_in[9];
    float* out = (float*)d_out;
    (void)d_ws; (void)ws_size;

    prepscatter_kernel<<<673, 256, 0, stream>>>(W1, W2, ei);
    stage1_kernel<<<(NN + 31) / 32, 256, 0, stream>>>(x, gamma, beta, mean, var, b1);
    edge_kernel<<<NN / 4, 256, 0, stream>>>(b2, out);
}